// Round 10
// baseline (239.471 us; speedup 1.0000x reference)
//
#include <hip/hip_runtime.h>

#define HD 1024
#define BB 64
#define II 512

typedef float f4 __attribute__((ext_vector_type(4)));

__device__ __forceinline__ float fast_tanh(float x) {
    float ax = __builtin_fabsf(x);
    float e  = __builtin_amdgcn_exp2f(ax * -2.8853900817779268f);  // exp(-2|x|)
    float t  = (1.0f - e) * __builtin_amdgcn_rcpf(1.0f + e);
    return x < 0.0f ? -t : t;
}

// out[b][h] = act( sum_k A[b][k] * W[h][k] + bias[h] ), act = tanh or identity
// Block = 1024 thr = 16 waves = 16 b's sharing one h-octet staged in LDS.
// grid 512 = 128 octets x 4 b-groups.
template <int K, bool TANH>
__global__ __launch_bounds__(1024) void k_gemm(const float* __restrict__ A,    // [64][K]
                                               const float* __restrict__ W,    // [1024][K]
                                               const float* __restrict__ bias, // [1024]
                                               float* __restrict__ out)        // [64][1024]
{
    constexpr int J = K / 256;
    __shared__ float wlds[8 * K];

    int tid  = threadIdx.x;
    int oct  = blockIdx.x & 127;
    int bg   = blockIdx.x >> 7;          // 0..3
    int h0   = oct * 8;

    {
        const f4* src = (const f4*)(W + (size_t)h0 * K);
        f4* dst = (f4*)wlds;
#pragma unroll
        for (int v = tid; v < 2 * K; v += 1024) dst[v] = src[v];
    }
    __syncthreads();

    int lane = tid & 63;
    int wave = tid >> 6;
    int b    = bg * 16 + wave;

    f4 a[J];
#pragma unroll
    for (int j = 0; j < J; ++j)
        a[j] = *(const f4*)(A + (size_t)b * K + j * 256 + lane * 4);

    float acc[8];
#pragma unroll
    for (int hh = 0; hh < 8; ++hh) {
        const float* wrow = wlds + hh * K;
        float s = 0.f;
#pragma unroll
        for (int j = 0; j < J; ++j) {
            f4 w4 = *(const f4*)(wrow + j * 256 + lane * 4);
            s += a[j].x * w4.x + a[j].y * w4.y + a[j].z * w4.z + a[j].w * w4.w;
        }
        acc[hh] = s;
    }
#pragma unroll
    for (int hh = 0; hh < 8; ++hh)
#pragma unroll
        for (int off = 32; off; off >>= 1)
            acc[hh] += __shfl_xor(acc[hh], off, 64);
    if (lane == 0) {
        f4 o0, o1;
        if (TANH) {
            o0.x = fast_tanh(acc[0] + bias[h0 + 0]);
            o0.y = fast_tanh(acc[1] + bias[h0 + 1]);
            o0.z = fast_tanh(acc[2] + bias[h0 + 2]);
            o0.w = fast_tanh(acc[3] + bias[h0 + 3]);
            o1.x = fast_tanh(acc[4] + bias[h0 + 4]);
            o1.y = fast_tanh(acc[5] + bias[h0 + 5]);
            o1.z = fast_tanh(acc[6] + bias[h0 + 6]);
            o1.w = fast_tanh(acc[7] + bias[h0 + 7]);
        } else {
            o0.x = acc[0] + bias[h0 + 0];
            o0.y = acc[1] + bias[h0 + 1];
            o0.z = acc[2] + bias[h0 + 2];
            o0.w = acc[3] + bias[h0 + 3];
            o1.x = acc[4] + bias[h0 + 4];
            o1.y = acc[5] + bias[h0 + 5];
            o1.z = acc[6] + bias[h0 + 6];
            o1.w = acc[7] + bias[h0 + 7];
        }
        *(f4*)(out + (size_t)b * HD + h0)     = o0;
        *(f4*)(out + (size_t)b * HD + h0 + 4) = o1;
    }
}

// A: plastic. grid 512 = (b, 128-h slice), 512 thr = 8 waves, 16 rows/wave,
// 2-row batches (16 f4 in flight). pw loads REGULAR (allocate in L3 for C).
__global__ __launch_bounds__(512, 4) void k_plastic(const float* __restrict__ pw,
                                                    const float* __restrict__ alpha,
                                                    const float* __restrict__ innate, // [64][1024]
                                                    const float* __restrict__ x2,     // [64][1024]
                                                    float* __restrict__ pre,          // [64][1024]
                                                    float* __restrict__ hidden)       // [64][1024]
{
    __shared__ float xs[HD];
    int tid   = threadIdx.x;
    int lane  = tid & 63;
    int wave  = tid >> 6;          // 0..7
    int b     = blockIdx.x >> 3;
    int sub   = blockIdx.x & 7;
    int hbase = sub << 7;

    if (tid < 256) ((f4*)xs)[tid] = ((const f4*)(x2 + ((size_t)b << 10)))[tid];
    __syncthreads();

#pragma unroll 1
    for (int rp = 0; rp < 8; ++rp) {
        int hl = (wave << 4) + (rp << 1);
        int h  = hbase + hl;
        const float* pr0 = pw + ((size_t)b << 20) + ((size_t)h << 10);
        const float* pr1 = pr0 + HD;
        const float* ar0 = alpha + ((size_t)h << 10);
        const float* ar1 = ar0 + HD;
        f4 p0[4], p1[4], a0[4], a1[4];
#pragma unroll
        for (int j = 0; j < 4; ++j) {
            int i = j * 256 + lane * 4;
            p0[j] = *(const f4*)(pr0 + i);
            p1[j] = *(const f4*)(pr1 + i);
            a0[j] = *(const f4*)(ar0 + i);
            a1[j] = *(const f4*)(ar1 + i);
        }
        float acc0 = 0.f, acc1 = 0.f;
#pragma unroll
        for (int j = 0; j < 4; ++j) {
            int i = j * 256 + lane * 4;
            f4 x4 = *(const f4*)(xs + i);
            acc0 += a0[j].x * p0[j].x * x4.x + a0[j].y * p0[j].y * x4.y +
                    a0[j].z * p0[j].z * x4.z + a0[j].w * p0[j].w * x4.w;
            acc1 += a1[j].x * p1[j].x * x4.x + a1[j].y * p1[j].y * x4.y +
                    a1[j].z * p1[j].z * x4.z + a1[j].w * p1[j].w * x4.w;
        }
#pragma unroll
        for (int off = 32; off; off >>= 1) {
            acc0 += __shfl_xor(acc0, off, 64);
            acc1 += __shfl_xor(acc1, off, 64);
        }
        if (lane == 0) {
            float pv0 = innate[(b << 10) + h]     + acc0;
            float pv1 = innate[(b << 10) + h + 1] + acc1;
            pre[(b << 10) + h]        = pv0;
            pre[(b << 10) + h + 1]    = pv1;
            hidden[(b << 10) + h]     = fast_tanh(pv0);
            hidden[(b << 10) + h + 1] = fast_tanh(pv1);
        }
    }
}

// B: heads. grid 64 x 1024 thr (16 waves). Wave w: 64 hrc rows (2-row batch).
// Fixed-order final reduce -> deterministic.
__global__ __launch_bounds__(1024) void k_heads(const float* __restrict__ hidden, // [64][1024]
                                                const float* __restrict__ reward, // [64]
                                                const float* __restrict__ Wr,     // [1024]
                                                const float* __restrict__ br,     // [1024]
                                                const float* __restrict__ Whr,
                                                const float* __restrict__ bhr,
                                                const float* __restrict__ Wnm,
                                                const float* __restrict__ bnm,
                                                const float* __restrict__ Wch,
                                                const float* __restrict__ bch,
                                                const float* __restrict__ Wv,
                                                const float* __restrict__ bv,
                                                float* __restrict__ out_choice,
                                                float* __restrict__ out_nm,
                                                float* __restrict__ out_value)
{
    __shared__ float hplus[HD];
    __shared__ float wred[16][4];
    int tid  = threadIdx.x;
    int lane = tid & 63;
    int wave = tid >> 6;           // 0..15
    int b    = blockIdx.x;

    hplus[tid] = hidden[(b << 10) + tid] + reward[b] * Wr[tid] + br[tid];
    __syncthreads();

    float nm0 = 0.f, nm1 = 0.f;
#pragma unroll 1
    for (int rp = 0; rp < 32; ++rp) {
        int h2 = (wave << 6) + (rp << 1);
        const float* w0 = Whr + ((size_t)h2 << 10);
        const float* w1 = w0 + HD;
        float s0 = 0.f, s1 = 0.f;
#pragma unroll
        for (int j = 0; j < 4; ++j) {
            int i = j * 256 + lane * 4;
            f4 wa = *(const f4*)(w0 + i);
            f4 wb = *(const f4*)(w1 + i);
            f4 h4 = *(const f4*)(hplus + i);
            s0 += wa.x * h4.x + wa.y * h4.y + wa.z * h4.z + wa.w * h4.w;
            s1 += wb.x * h4.x + wb.y * h4.y + wb.z * h4.z + wb.w * h4.w;
        }
#pragma unroll
        for (int off = 32; off; off >>= 1) {
            s0 += __shfl_xor(s0, off, 64);
            s1 += __shfl_xor(s1, off, 64);
        }
        if (lane == 0) {
            float hr0 = fast_tanh(s0 + bhr[h2]);
            float hr1 = fast_tanh(s1 + bhr[h2 + 1]);
            nm0 += Wnm[h2] * hr0 + Wnm[h2 + 1] * hr1;
            nm1 += Wnm[HD + h2] * hr0 + Wnm[HD + h2 + 1] * hr1;
        }
    }
    // choice/value partials: idx = wave*64 + lane covers 0..1023
    int idx = (wave << 6) + lane;
    float hv = hidden[(b << 10) + idx];
    float cv = Wch[idx] * hv;
    float vv = Wv[idx] * hv;
#pragma unroll
    for (int off = 32; off; off >>= 1) {
        cv += __shfl_xor(cv, off, 64);
        vv += __shfl_xor(vv, off, 64);
    }
    if (lane == 0) {
        wred[wave][0] = nm0; wred[wave][1] = nm1;
        wred[wave][2] = cv;  wred[wave][3] = vv;
    }
    __syncthreads();
    if (tid == 0) {
        float s0 = 0.f, s1 = 0.f, s2 = 0.f, s3 = 0.f;
        for (int w = 0; w < 16; ++w) {          // fixed order -> deterministic
            s0 += wred[w][0]; s1 += wred[w][1];
            s2 += wred[w][2]; s3 += wred[w][3];
        }
        float n0 = fast_tanh(s0 + bnm[0]);
        float n1 = fast_tanh(s1 + bnm[1]);
        out_nm[b] = n0 - n1;
        float z = s2 + bch[0];
        out_choice[b] = __builtin_amdgcn_rcpf(1.0f + __builtin_amdgcn_exp2f(-z * 1.4426950408889634f));
        out_value[b]  = s3 + bv[0];
    }
}

// C: update. 8192 blocks x 256 thr x 8 f4. pw re-read should hit L3 (read by A
// moments ago; pw exactly fits the 256 MB L3). Regular loads; NT stores.
__global__ __launch_bounds__(256) void k_update(const float* __restrict__ pw,
                                                const float* __restrict__ pre, // [64][1024]
                                                const float* __restrict__ x,   // [64][1024]
                                                const float* __restrict__ nm,  // [64]
                                                float* __restrict__ out) {
    int f0 = blockIdx.x * 256 + threadIdx.x;
    const int stride = 8192 * 256;   // 2,097,152 f4 per stripe
#pragma unroll
    for (int it = 0; it < 8; ++it) {
        int f = f0 + it * stride;
        size_t e = (size_t)f << 2;
        int b = f >> 18;
        int h = (f >> 8) & 1023;
        int i = (f & 255) << 2;
        f4 p4 = *(const f4*)(pw + e);
        f4 x4 = *(const f4*)(x + (b << 10) + i);
        float ps = pre[(b << 10) + h];
        float nb = nm[b];
        f4 o4;
        o4.x = fminf(fmaxf(p4.x + nb * fast_tanh(ps * x4.x), -50.f), 50.f);
        o4.y = fminf(fmaxf(p4.y + nb * fast_tanh(ps * x4.y), -50.f), 50.f);
        o4.z = fminf(fmaxf(p4.z + nb * fast_tanh(ps * x4.z), -50.f), 50.f);
        o4.w = fminf(fmaxf(p4.w + nb * fast_tanh(ps * x4.w), -50.f), 50.f);
        __builtin_nontemporal_store(o4, (f4*)(out + e));
    }
}

extern "C" void kernel_launch(void* const* d_in, const int* in_sizes, int n_in,
                              void* d_out, int out_size, void* d_ws, size_t ws_size,
                              hipStream_t stream) {
    const float* items  = (const float*)d_in[0];
    const float* pw     = (const float*)d_in[1];
    const float* reward = (const float*)d_in[2];
    const float* We     = (const float*)d_in[3];
    const float* be     = (const float*)d_in[4];
    const float* W1     = (const float*)d_in[5];
    const float* b1     = (const float*)d_in[6];
    const float* W2     = (const float*)d_in[7];
    const float* b2     = (const float*)d_in[8];
    const float* Wfc2   = (const float*)d_in[9];
    const float* bfc2   = (const float*)d_in[10];
    const float* Whr    = (const float*)d_in[11];
    const float* bhr    = (const float*)d_in[12];
    const float* Wch    = (const float*)d_in[13];
    const float* bch    = (const float*)d_in[14];
    const float* Wr     = (const float*)d_in[15];
    const float* br     = (const float*)d_in[16];
    const float* Wnm    = (const float*)d_in[17];
    const float* bnm    = (const float*)d_in[18];
    const float* alpha  = (const float*)d_in[19];
    const float* Wv     = (const float*)d_in[20];
    const float* bv     = (const float*)d_in[21];

    float* ws     = (float*)d_ws;
    float* x0     = ws;                   // 65536
    float* x1     = ws + 65536;           // 65536
    float* x2     = ws + 131072;          // 65536
    float* innate = ws + 196608;          // 65536
    float* preb   = ws + 262144;          // 65536

    float* out        = (float*)d_out;
    float* out_choice = out;                        // 64
    float* out_nm     = out + 64;                   // 64
    float* out_value  = out + 128;                  // 64
    float* out_newpw  = out + 192;                  // 67,108,864
    float* out_hidden = out + 192 + BB * HD * HD;   // 65,536

    k_gemm<II, true ><<<512, 1024, 0, stream>>>(items, We, be, x0);
    k_gemm<HD, true ><<<512, 1024, 0, stream>>>(x0, W1, b1, x1);
    k_gemm<HD, true ><<<512, 1024, 0, stream>>>(x1, W2, b2, x2);
    k_gemm<HD, false><<<512, 1024, 0, stream>>>(x2, Wfc2, bfc2, innate);
    k_plastic<<<512, 512, 0, stream>>>(pw, alpha, innate, x2, preb, out_hidden);
    k_heads<<<64, 1024, 0, stream>>>(out_hidden, reward, Wr, br, Whr, bhr,
                                     Wnm, bnm, Wch, bch, Wv, bv,
                                     out_choice, out_nm, out_value);
    k_update<<<8192, 256, 0, stream>>>(pw, preb, x2, out_nm, out_newpw);
}